// Round 2
// baseline (43264.310 us; speedup 1.0000x reference)
//
#include <hip/hip_runtime.h>
#include <stdint.h>

#define TB 512

// ---------------- JAX threefry2x32 (exact) ----------------
__device__ __forceinline__ uint32_t rotl32(uint32_t v, int s) {
    return (v << s) | (v >> (32 - s));
}

__device__ __forceinline__ void threefry2x32(uint32_t k0, uint32_t k1,
                                             uint32_t c0, uint32_t c1,
                                             uint32_t& o0, uint32_t& o1) {
    const uint32_t ks2 = k0 ^ k1 ^ 0x1BD11BDAu;
    uint32_t x0 = c0 + k0;
    uint32_t x1 = c1 + k1;
    // round group 1: rot(13,15,26,6), inject (k1, ks2+1)
    x0 += x1; x1 = rotl32(x1, 13); x1 ^= x0;
    x0 += x1; x1 = rotl32(x1, 15); x1 ^= x0;
    x0 += x1; x1 = rotl32(x1, 26); x1 ^= x0;
    x0 += x1; x1 = rotl32(x1, 6);  x1 ^= x0;
    x0 += k1;  x1 += ks2 + 1u;
    // group 2: rot(17,29,16,24), inject (ks2, k0+2)
    x0 += x1; x1 = rotl32(x1, 17); x1 ^= x0;
    x0 += x1; x1 = rotl32(x1, 29); x1 ^= x0;
    x0 += x1; x1 = rotl32(x1, 16); x1 ^= x0;
    x0 += x1; x1 = rotl32(x1, 24); x1 ^= x0;
    x0 += ks2; x1 += k0 + 2u;
    // group 3: rot(13,15,26,6), inject (k0, k1+3)
    x0 += x1; x1 = rotl32(x1, 13); x1 ^= x0;
    x0 += x1; x1 = rotl32(x1, 15); x1 ^= x0;
    x0 += x1; x1 = rotl32(x1, 26); x1 ^= x0;
    x0 += x1; x1 = rotl32(x1, 6);  x1 ^= x0;
    x0 += k0;  x1 += k1 + 3u;
    // group 4: rot(17,29,16,24), inject (k1, ks2+4)
    x0 += x1; x1 = rotl32(x1, 17); x1 ^= x0;
    x0 += x1; x1 = rotl32(x1, 29); x1 ^= x0;
    x0 += x1; x1 = rotl32(x1, 16); x1 ^= x0;
    x0 += x1; x1 = rotl32(x1, 24); x1 ^= x0;
    x0 += k1;  x1 += ks2 + 4u;
    // group 5: rot(13,15,26,6), inject (ks2, k0+5)
    x0 += x1; x1 = rotl32(x1, 13); x1 ^= x0;
    x0 += x1; x1 = rotl32(x1, 15); x1 ^= x0;
    x0 += x1; x1 = rotl32(x1, 26); x1 ^= x0;
    x0 += x1; x1 = rotl32(x1, 6);  x1 ^= x0;
    x0 += ks2; x1 += k0 + 5u;
    o0 = x0; o1 = x1;
}

// jax_threefry_partitionable=True (default since jax 0.4.36):
// random_bits elem i (size < 2^32): counter = (0, i), bits = w0 ^ w1.
__device__ __forceinline__ uint32_t jax_random_bits(uint32_t k0, uint32_t k1, uint32_t i) {
    uint32_t o0, o1;
    threefry2x32(k0, k1, 0u, i, o0, o1);
    return o0 ^ o1;
}

// XLA f32 ErfInv (Giles polynomial) — matches jax.lax.erf_inv float32
__device__ __forceinline__ float erfinv_f32(float x) {
    float w = -log1pf(-x * x);
    float p;
    if (w < 5.0f) {
        w = w - 2.5f;
        p = 2.81022636e-08f;
        p = fmaf(p, w, 3.43273939e-07f);
        p = fmaf(p, w, -3.5233877e-06f);
        p = fmaf(p, w, -4.39150654e-06f);
        p = fmaf(p, w, 0.00021858087f);
        p = fmaf(p, w, -0.00125372503f);
        p = fmaf(p, w, -0.00417768164f);
        p = fmaf(p, w, 0.246640727f);
        p = fmaf(p, w, 1.50140941f);
    } else {
        w = sqrtf(w) - 3.0f;
        p = -0.000200214257f;
        p = fmaf(p, w, 0.000100950558f);
        p = fmaf(p, w, 0.00134934322f);
        p = fmaf(p, w, -0.00367342844f);
        p = fmaf(p, w, 0.00573950773f);
        p = fmaf(p, w, -0.0076224613f);
        p = fmaf(p, w, 0.00943887047f);
        p = fmaf(p, w, 1.00167406f);
        p = fmaf(p, w, 2.83297682f);
    }
    return p * x;
}

// jax.random.normal f32: uniform in (lo=-0.99999994, 1.0) then sqrt(2)*erfinv.
// (hi-lo) rounds to exactly 2.0f in f32, so fma(f,2,lo) == (f*2)+lo exactly.
__device__ __forceinline__ float normal_from_bits(uint32_t bits) {
    float f = __uint_as_float((bits >> 9) | 0x3F800000u) - 1.0f;  // [0,1)
    float uu = fmaxf(-0.99999994f, fmaf(f, 2.0f, -0.99999994f));
    return 1.41421354f * erfinv_f32(uu);
}

// jax.random.gumbel f32: -log(-log(uniform(minval=FLT_TINY, maxval=1)))
__device__ __forceinline__ float gumbel_from_bits(uint32_t bits) {
    float f = __uint_as_float((bits >> 9) | 0x3F800000u) - 1.0f;
    float uu = fmaxf(1.17549435e-38f, f + 1.17549435e-38f);
    return -logf(-logf(uu));
}

__device__ __forceinline__ float jax_normal_elem(uint32_t k0, uint32_t k1, uint32_t i) {
    return normal_from_bits(jax_random_bits(k0, k1, i));
}

// ---------------- SMC kernel: one block per batch element ----------------
__global__ __launch_bounds__(TB) void smc_kernel(
    const float* __restrict__ u, const float* __restrict__ y,
    const float* __restrict__ W_ih, const float* __restrict__ W_hh,
    const float* __restrict__ b_ih, const float* __restrict__ b_hh,
    const float* __restrict__ W1, const float* __restrict__ b1,
    const float* __restrict__ W2, const float* __restrict__ b2,
    const float* __restrict__ sigx, const float* __restrict__ sigy,
    float* __restrict__ out) {
    const int b = blockIdx.x;     // batch element
    const int tid = threadIdx.x;

    // padded to 68 cols: stagger rows across banks; rows stay 16B-aligned (272B)
    __shared__ __align__(16) float xs[128][68];   // state; reused as h buffer
    __shared__ __align__(16) float xn[128][68];   // post-noise state
    __shared__ __align__(16) float Wihs[64][68];
    __shared__ __align__(16) float Whh[64][68];
    __shared__ __align__(16) float W1s[64][68];
    __shared__ __align__(16) float W2s[64][16];
    __shared__ __align__(16) float yh[128][16];
    __shared__ float logw[128];
    __shared__ float ubp[64];
    __shared__ float bhhs[64], b1s[64], b2s[16], stdxv[64], stdyv[16], sigyv[16], ykv[16];
    __shared__ int   anc[128];

    for (int i = tid; i < 4096; i += TB) {
        const int r = i >> 6, c = i & 63;
        Wihs[r][c] = W_ih[i];
        Whh[r][c]  = W_hh[i];
        W1s[r][c]  = W1[i];
    }
    for (int i = tid; i < 1024; i += TB) W2s[i >> 4][i & 15] = W2[i];
    if (tid < 64) { bhhs[tid] = b_hh[tid]; b1s[tid] = b1[tid]; stdxv[tid] = sqrtf(sigx[tid]); }
    if (tid < 16) { b2s[tid] = b2[tid]; sigyv[tid] = sigy[tid]; stdyv[tid] = sqrtf(sigy[tid]); }

    // x0 = normal(fold_in(key(42), 2^20), (64,128,64)); fold_in = cipher(k,0,data)
    {
        uint32_t xk0, xk1;
        threefry2x32(0u, 42u, 0u, 1048576u, xk0, xk1);
        for (int it = tid; it < 8192; it += TB) {
            const uint32_t idx = (uint32_t)b * 8192u + (uint32_t)it;
            xs[it >> 6][it & 63] = jax_normal_elem(xk0, xk1, idx);
        }
    }
    __syncthreads();

    for (int t = 0; t < 256; ++t) {
        // k = fold_in(base, t); split(k,3) foldlike: key_i = cipher(k, 0, i)
        uint32_t kk0, kk1, kx0, kx1, ky0, ky1, kc0, kc1;
        threefry2x32(0u, 42u, 0u, (uint32_t)t, kk0, kk1);
        threefry2x32(kk0, kk1, 0u, 0u, kx0, kx1);  // k1 -> state noise
        threefry2x32(kk0, kk1, 0u, 1u, ky0, ky1);  // k2 -> obs noise
        threefry2x32(kk0, kk1, 0u, 2u, kc0, kc1);  // k3 -> categorical

        const float* ut = u + ((size_t)t * 64 + b) * 64;
        const float* yt = y + ((size_t)t * 64 + b) * 16;
        // phase 1: ubp[d] = dot(u_t, W_ih[:,d]) + b_ih[d]
        if (tid < 64) {
            float s = 0.f;
            #pragma unroll
            for (int k = 0; k < 64; ++k) s = fmaf(ut[k], Wihs[k][tid], s);
            ubp[tid] = s + b_ih[tid];
        }
        if (tid < 16) ykv[tid] = yt[tid];
        __syncthreads();

        // phase 2: xn = tanh((ubp + xs@Whh) + bhh) + stdx*noise  (4n x 4d per thread)
        {
            const int n0 = (tid >> 4) * 4;
            const int d0 = (tid & 15) * 4;
            float acc[4][4];
            #pragma unroll
            for (int i = 0; i < 4; ++i)
                #pragma unroll
                for (int j = 0; j < 4; ++j) acc[i][j] = 0.f;
            for (int k4 = 0; k4 < 64; k4 += 4) {
                float4 a[4];
                #pragma unroll
                for (int i = 0; i < 4; ++i) a[i] = *(const float4*)&xs[n0 + i][k4];
                #pragma unroll
                for (int kk = 0; kk < 4; ++kk) {
                    const float4 wr = *(const float4*)&Whh[k4 + kk][d0];
                    #pragma unroll
                    for (int i = 0; i < 4; ++i) {
                        const float av = (&a[i].x)[kk];
                        acc[i][0] = fmaf(av, wr.x, acc[i][0]);
                        acc[i][1] = fmaf(av, wr.y, acc[i][1]);
                        acc[i][2] = fmaf(av, wr.z, acc[i][2]);
                        acc[i][3] = fmaf(av, wr.w, acc[i][3]);
                    }
                }
            }
            #pragma unroll
            for (int i = 0; i < 4; ++i) {
                const int n = n0 + i;
                float4 res;
                #pragma unroll
                for (int j = 0; j < 4; ++j) {
                    const int d = d0 + j;
                    const float v = tanhf((ubp[d] + acc[i][j]) + bhhs[d]);
                    const uint32_t idx = (uint32_t)(b * 8192 + n * 64 + d);
                    const float nz = jax_normal_elem(kx0, kx1, idx);
                    (&res.x)[j] = v + stdxv[d] * nz;
                }
                *(float4*)&xn[n][d0] = res;
            }
        }
        __syncthreads();

        // phase 3: h = relu(xn@W1 + b1) into xs (old state dead)
        {
            const int n0 = (tid >> 4) * 4;
            const int d0 = (tid & 15) * 4;
            float acc[4][4];
            #pragma unroll
            for (int i = 0; i < 4; ++i)
                #pragma unroll
                for (int j = 0; j < 4; ++j) acc[i][j] = 0.f;
            for (int k4 = 0; k4 < 64; k4 += 4) {
                float4 a[4];
                #pragma unroll
                for (int i = 0; i < 4; ++i) a[i] = *(const float4*)&xn[n0 + i][k4];
                #pragma unroll
                for (int kk = 0; kk < 4; ++kk) {
                    const float4 wr = *(const float4*)&W1s[k4 + kk][d0];
                    #pragma unroll
                    for (int i = 0; i < 4; ++i) {
                        const float av = (&a[i].x)[kk];
                        acc[i][0] = fmaf(av, wr.x, acc[i][0]);
                        acc[i][1] = fmaf(av, wr.y, acc[i][1]);
                        acc[i][2] = fmaf(av, wr.z, acc[i][2]);
                        acc[i][3] = fmaf(av, wr.w, acc[i][3]);
                    }
                }
            }
            #pragma unroll
            for (int i = 0; i < 4; ++i) {
                float4 res;
                #pragma unroll
                for (int j = 0; j < 4; ++j)
                    (&res.x)[j] = fmaxf(acc[i][j] + b1s[d0 + j], 0.0f);
                *(float4*)&xs[n0 + i][d0] = res;
            }
        }
        __syncthreads();

        // phase 4: y_hat = h@W2 + b2 + stdy*noise; write output (1n x 4d per thread)
        {
            const int n = tid >> 2;
            const int d0 = (tid & 3) * 4;
            float4 acc = make_float4(0.f, 0.f, 0.f, 0.f);
            for (int j4 = 0; j4 < 64; j4 += 4) {
                const float4 h4 = *(const float4*)&xs[n][j4];
                #pragma unroll
                for (int jj = 0; jj < 4; ++jj) {
                    const float4 wr = *(const float4*)&W2s[j4 + jj][d0];
                    const float hv = (&h4.x)[jj];
                    acc.x = fmaf(hv, wr.x, acc.x);
                    acc.y = fmaf(hv, wr.y, acc.y);
                    acc.z = fmaf(hv, wr.z, acc.z);
                    acc.w = fmaf(hv, wr.w, acc.w);
                }
            }
            float4 res;
            #pragma unroll
            for (int j = 0; j < 4; ++j) {
                const int d = d0 + j;
                const float v = (&acc.x)[j] + b2s[d];
                const uint32_t idx = (uint32_t)(b * 2048 + n * 16 + d);
                const float nz = jax_normal_elem(ky0, ky1, idx);
                const float yhv = v + stdyv[d] * nz;
                yh[n][d] = yhv;
                (&res.x)[j] = yhv;
            }
            *(float4*)&out[(((size_t)t * 64 + b) * 128 + n) * 16 + d0] = res;
        }
        __syncthreads();

        // phase 5: logw (constant shift terms cancel in argmax; omit them)
        if (tid < 128) {
            float s = 0.f;
            for (int d = 0; d < 16; ++d) {
                const float dd = yh[tid][d] - ykv[d];
                s += (dd * dd) / sigyv[d];
            }
            logw[tid] = -0.5f * s;
        }
        __syncthreads();

        // phase 6: categorical via gumbel argmax. gumbel shape (128,64,128),
        // flat idx = p*8192 + b*128 + n, one cipher per element (partitionable).
        {
            const int p = tid >> 2;   // draw row 0..127
            const int sub = tid & 3;  // 4 threads per draw, 32 categories each
            float best = -3.402823466e+38f;
            int bi = 0;
            const uint32_t base_idx = (uint32_t)p * 8192u + (uint32_t)b * 128u;
            for (int m = 0; m < 32; ++m) {
                const int n = (sub << 5) + m;
                const float v = logw[n] + gumbel_from_bits(jax_random_bits(kc0, kc1, base_idx + (uint32_t)n));
                if (v > best) { best = v; bi = n; }
            }
            #pragma unroll
            for (int off = 1; off < 4; off <<= 1) {
                const float ov = __shfl_xor(best, off);
                const int   oi = __shfl_xor(bi, off);
                if (ov > best || (ov == best && oi < bi)) { best = ov; bi = oi; }
            }
            if (sub == 0) anc[p] = bi;
        }
        __syncthreads();

        // phase 7: resample xs[n] = xn[anc[n]]
        for (int it = tid; it < 2048; it += TB) {
            const int n = it >> 4, q = (it & 15) * 4;
            *(float4*)&xs[n][q] = *(const float4*)&xn[anc[n]][q];
        }
        __syncthreads();
    }
}

extern "C" void kernel_launch(void* const* d_in, const int* in_sizes, int n_in,
                              void* d_out, int out_size, void* d_ws, size_t ws_size,
                              hipStream_t stream) {
    const float* u    = (const float*)d_in[0];
    const float* y    = (const float*)d_in[1];
    const float* W_ih = (const float*)d_in[2];
    const float* W_hh = (const float*)d_in[3];
    const float* b_ih = (const float*)d_in[4];
    const float* b_hh = (const float*)d_in[5];
    const float* W1   = (const float*)d_in[6];
    const float* b1   = (const float*)d_in[7];
    const float* W2   = (const float*)d_in[8];
    const float* b2   = (const float*)d_in[9];
    const float* sigx = (const float*)d_in[10];
    const float* sigy = (const float*)d_in[11];
    float* out = (float*)d_out;
    hipLaunchKernelGGL(smc_kernel, dim3(64), dim3(TB), 0, stream,
                       u, y, W_ih, W_hh, b_ih, b_hh, W1, b1, W2, b2, sigx, sigy, out);
}

// Round 3
// 10609.055 us; speedup vs baseline: 4.0781x; 4.0781x over previous
//
#include <hip/hip_runtime.h>
#include <stdint.h>

#define TB 512

// ---------------- JAX threefry2x32 (exact) ----------------
__device__ __forceinline__ uint32_t rotl32(uint32_t v, int s) {
    return (v << s) | (v >> (32 - s));
}

__device__ __forceinline__ void threefry2x32(uint32_t k0, uint32_t k1,
                                             uint32_t c0, uint32_t c1,
                                             uint32_t& o0, uint32_t& o1) {
    const uint32_t ks2 = k0 ^ k1 ^ 0x1BD11BDAu;
    uint32_t x0 = c0 + k0;
    uint32_t x1 = c1 + k1;
    // round group 1: rot(13,15,26,6), inject (k1, ks2+1)
    x0 += x1; x1 = rotl32(x1, 13); x1 ^= x0;
    x0 += x1; x1 = rotl32(x1, 15); x1 ^= x0;
    x0 += x1; x1 = rotl32(x1, 26); x1 ^= x0;
    x0 += x1; x1 = rotl32(x1, 6);  x1 ^= x0;
    x0 += k1;  x1 += ks2 + 1u;
    // group 2: rot(17,29,16,24), inject (ks2, k0+2)
    x0 += x1; x1 = rotl32(x1, 17); x1 ^= x0;
    x0 += x1; x1 = rotl32(x1, 29); x1 ^= x0;
    x0 += x1; x1 = rotl32(x1, 16); x1 ^= x0;
    x0 += x1; x1 = rotl32(x1, 24); x1 ^= x0;
    x0 += ks2; x1 += k0 + 2u;
    // group 3: rot(13,15,26,6), inject (k0, k1+3)
    x0 += x1; x1 = rotl32(x1, 13); x1 ^= x0;
    x0 += x1; x1 = rotl32(x1, 15); x1 ^= x0;
    x0 += x1; x1 = rotl32(x1, 26); x1 ^= x0;
    x0 += x1; x1 = rotl32(x1, 6);  x1 ^= x0;
    x0 += k0;  x1 += k1 + 3u;
    // group 4: rot(17,29,16,24), inject (k1, ks2+4)
    x0 += x1; x1 = rotl32(x1, 17); x1 ^= x0;
    x0 += x1; x1 = rotl32(x1, 29); x1 ^= x0;
    x0 += x1; x1 = rotl32(x1, 16); x1 ^= x0;
    x0 += x1; x1 = rotl32(x1, 24); x1 ^= x0;
    x0 += k1;  x1 += ks2 + 4u;
    // group 5: rot(13,15,26,6), inject (ks2, k0+5)
    x0 += x1; x1 = rotl32(x1, 13); x1 ^= x0;
    x0 += x1; x1 = rotl32(x1, 15); x1 ^= x0;
    x0 += x1; x1 = rotl32(x1, 26); x1 ^= x0;
    x0 += x1; x1 = rotl32(x1, 6);  x1 ^= x0;
    x0 += ks2; x1 += k0 + 5u;
    o0 = x0; o1 = x1;
}

// jax_threefry_partitionable=True (default since jax 0.4.36):
// random_bits elem i (size < 2^32): counter = (0, i), bits = w0 ^ w1.
__device__ __forceinline__ uint32_t jax_random_bits(uint32_t k0, uint32_t k1, uint32_t i) {
    uint32_t o0, o1;
    threefry2x32(k0, k1, 0u, i, o0, o1);
    return o0 ^ o1;
}

// XLA f32 ErfInv (Giles polynomial) — matches jax.lax.erf_inv float32
__device__ __forceinline__ float erfinv_f32(float x) {
    float w = -log1pf(-x * x);
    float p;
    if (w < 5.0f) {
        w = w - 2.5f;
        p = 2.81022636e-08f;
        p = fmaf(p, w, 3.43273939e-07f);
        p = fmaf(p, w, -3.5233877e-06f);
        p = fmaf(p, w, -4.39150654e-06f);
        p = fmaf(p, w, 0.00021858087f);
        p = fmaf(p, w, -0.00125372503f);
        p = fmaf(p, w, -0.00417768164f);
        p = fmaf(p, w, 0.246640727f);
        p = fmaf(p, w, 1.50140941f);
    } else {
        w = sqrtf(w) - 3.0f;
        p = -0.000200214257f;
        p = fmaf(p, w, 0.000100950558f);
        p = fmaf(p, w, 0.00134934322f);
        p = fmaf(p, w, -0.00367342844f);
        p = fmaf(p, w, 0.00573950773f);
        p = fmaf(p, w, -0.0076224613f);
        p = fmaf(p, w, 0.00943887047f);
        p = fmaf(p, w, 1.00167406f);
        p = fmaf(p, w, 2.83297682f);
    }
    return p * x;
}

// jax.random.normal f32: uniform in (lo=-0.99999994, 1.0) then sqrt(2)*erfinv.
__device__ __forceinline__ float normal_from_bits(uint32_t bits) {
    float f = __uint_as_float((bits >> 9) | 0x3F800000u) - 1.0f;  // [0,1)
    float uu = fmaxf(-0.99999994f, fmaf(f, 2.0f, -0.99999994f));
    return 1.41421354f * erfinv_f32(uu);
}

// jax.random.gumbel f32: -log(-log(uniform(minval=FLT_TINY, maxval=1)))
__device__ __forceinline__ float gumbel_from_bits(uint32_t bits) {
    float f = __uint_as_float((bits >> 9) | 0x3F800000u) - 1.0f;
    float uu = fmaxf(1.17549435e-38f, f + 1.17549435e-38f);
    return -logf(-logf(uu));
}

__device__ __forceinline__ float jax_normal_elem(uint32_t k0, uint32_t k1, uint32_t i) {
    return normal_from_bits(jax_random_bits(k0, k1, i));
}

// ---------------- SMC kernel: one block per batch element ----------------
// __launch_bounds__(512, 2): 136KB LDS already limits us to 1 block/CU
// (= 2 waves/EU for 512 threads), so tell the register allocator — raises
// the VGPR cap from the 128 default-heuristic to ~256 and removes the
// spill motive (r2 theory: 21 GB/dispatch scratch traffic from spills).
__global__ __launch_bounds__(TB, 2) void smc_kernel(
    const float* __restrict__ u, const float* __restrict__ y,
    const float* __restrict__ W_ih, const float* __restrict__ W_hh,
    const float* __restrict__ b_ih, const float* __restrict__ b_hh,
    const float* __restrict__ W1, const float* __restrict__ b1,
    const float* __restrict__ W2, const float* __restrict__ b2,
    const float* __restrict__ sigx, const float* __restrict__ sigy,
    float* __restrict__ out) {
    const int b = blockIdx.x;     // batch element
    const int tid = threadIdx.x;

    // padded to 68 cols: stagger rows across banks; rows stay 16B-aligned (272B)
    __shared__ __align__(16) float xs[128][68];   // state; reused as h buffer
    __shared__ __align__(16) float xn[128][68];   // post-noise state
    __shared__ __align__(16) float Wihs[64][68];
    __shared__ __align__(16) float Whh[64][68];
    __shared__ __align__(16) float W1s[64][68];
    __shared__ __align__(16) float W2s[64][16];
    __shared__ __align__(16) float yh[128][16];
    __shared__ float logw[128];
    __shared__ float ubp[64];
    __shared__ float bhhs[64], b1s[64], b2s[16], stdxv[64], stdyv[16], sigyv[16], ykv[16];
    __shared__ int   anc[128];

    for (int i = tid; i < 4096; i += TB) {
        const int r = i >> 6, c = i & 63;
        Wihs[r][c] = W_ih[i];
        Whh[r][c]  = W_hh[i];
        W1s[r][c]  = W1[i];
    }
    for (int i = tid; i < 1024; i += TB) W2s[i >> 4][i & 15] = W2[i];
    if (tid < 64) { bhhs[tid] = b_hh[tid]; b1s[tid] = b1[tid]; stdxv[tid] = sqrtf(sigx[tid]); }
    if (tid < 16) { b2s[tid] = b2[tid]; sigyv[tid] = sigy[tid]; stdyv[tid] = sqrtf(sigy[tid]); }

    // x0 = normal(fold_in(key(42), 2^20), (64,128,64)); fold_in = cipher(k,0,data)
    {
        uint32_t xk0, xk1;
        threefry2x32(0u, 42u, 0u, 1048576u, xk0, xk1);
        for (int it = tid; it < 8192; it += TB) {
            const uint32_t idx = (uint32_t)b * 8192u + (uint32_t)it;
            xs[it >> 6][it & 63] = jax_normal_elem(xk0, xk1, idx);
        }
    }
    __syncthreads();

    for (int t = 0; t < 256; ++t) {
        // k = fold_in(base, t); split(k,3) foldlike: key_i = cipher(k, 0, i)
        uint32_t kk0, kk1, kx0, kx1, ky0, ky1, kc0, kc1;
        threefry2x32(0u, 42u, 0u, (uint32_t)t, kk0, kk1);
        threefry2x32(kk0, kk1, 0u, 0u, kx0, kx1);  // k1 -> state noise
        threefry2x32(kk0, kk1, 0u, 1u, ky0, ky1);  // k2 -> obs noise
        threefry2x32(kk0, kk1, 0u, 2u, kc0, kc1);  // k3 -> categorical

        const float* ut = u + ((size_t)t * 64 + b) * 64;
        const float* yt = y + ((size_t)t * 64 + b) * 16;
        // phase 1: ubp[d] = dot(u_t, W_ih[:,d]) + b_ih[d]
        if (tid < 64) {
            float s = 0.f;
            #pragma unroll 4
            for (int k = 0; k < 64; ++k) s = fmaf(ut[k], Wihs[k][tid], s);
            ubp[tid] = s + b_ih[tid];
        }
        if (tid < 16) ykv[tid] = yt[tid];
        __syncthreads();

        // phase 2a: xn = tanh((ubp + xs@Whh) + bhh)  (4n x 4d per thread)
        {
            const int n0 = (tid >> 4) * 4;
            const int d0 = (tid & 15) * 4;
            float acc[4][4];
            #pragma unroll
            for (int i = 0; i < 4; ++i)
                #pragma unroll
                for (int j = 0; j < 4; ++j) acc[i][j] = 0.f;
            #pragma unroll 4
            for (int k4 = 0; k4 < 64; k4 += 4) {
                float4 a[4];
                #pragma unroll
                for (int i = 0; i < 4; ++i) a[i] = *(const float4*)&xs[n0 + i][k4];
                #pragma unroll
                for (int kk = 0; kk < 4; ++kk) {
                    const float4 wr = *(const float4*)&Whh[k4 + kk][d0];
                    #pragma unroll
                    for (int i = 0; i < 4; ++i) {
                        const float av = (&a[i].x)[kk];
                        acc[i][0] = fmaf(av, wr.x, acc[i][0]);
                        acc[i][1] = fmaf(av, wr.y, acc[i][1]);
                        acc[i][2] = fmaf(av, wr.z, acc[i][2]);
                        acc[i][3] = fmaf(av, wr.w, acc[i][3]);
                    }
                }
            }
            #pragma unroll
            for (int i = 0; i < 4; ++i) {
                const int n = n0 + i;
                float4 res;
                #pragma unroll
                for (int j = 0; j < 4; ++j) {
                    const int d = d0 + j;
                    (&res.x)[j] = tanhf((ubp[d] + acc[i][j]) + bhhs[d]);
                }
                *(float4*)&xn[n][d0] = res;
            }
            // phase 2b (same thread, same tile — no barrier needed):
            // xn += stdx * noise. acc[][] is dead here, so the 16 RNG chains
            // never coexist with the GEMM live ranges.
            #pragma unroll
            for (int i = 0; i < 4; ++i) {
                const int n = n0 + i;
                float4 v = *(const float4*)&xn[n][d0];
                #pragma unroll
                for (int j = 0; j < 4; ++j) {
                    const int d = d0 + j;
                    const uint32_t idx = (uint32_t)(b * 8192 + n * 64 + d);
                    const float nz = jax_normal_elem(kx0, kx1, idx);
                    (&v.x)[j] = (&v.x)[j] + stdxv[d] * nz;
                }
                *(float4*)&xn[n][d0] = v;
            }
        }
        __syncthreads();

        // phase 3: h = relu(xn@W1 + b1) into xs (old state dead)
        {
            const int n0 = (tid >> 4) * 4;
            const int d0 = (tid & 15) * 4;
            float acc[4][4];
            #pragma unroll
            for (int i = 0; i < 4; ++i)
                #pragma unroll
                for (int j = 0; j < 4; ++j) acc[i][j] = 0.f;
            #pragma unroll 4
            for (int k4 = 0; k4 < 64; k4 += 4) {
                float4 a[4];
                #pragma unroll
                for (int i = 0; i < 4; ++i) a[i] = *(const float4*)&xn[n0 + i][k4];
                #pragma unroll
                for (int kk = 0; kk < 4; ++kk) {
                    const float4 wr = *(const float4*)&W1s[k4 + kk][d0];
                    #pragma unroll
                    for (int i = 0; i < 4; ++i) {
                        const float av = (&a[i].x)[kk];
                        acc[i][0] = fmaf(av, wr.x, acc[i][0]);
                        acc[i][1] = fmaf(av, wr.y, acc[i][1]);
                        acc[i][2] = fmaf(av, wr.z, acc[i][2]);
                        acc[i][3] = fmaf(av, wr.w, acc[i][3]);
                    }
                }
            }
            #pragma unroll
            for (int i = 0; i < 4; ++i) {
                float4 res;
                #pragma unroll
                for (int j = 0; j < 4; ++j)
                    (&res.x)[j] = fmaxf(acc[i][j] + b1s[d0 + j], 0.0f);
                *(float4*)&xs[n0 + i][d0] = res;
            }
        }
        __syncthreads();

        // phase 4: y_hat = h@W2 + b2 + stdy*noise; write output (1n x 4d per thread)
        {
            const int n = tid >> 2;
            const int d0 = (tid & 3) * 4;
            float4 acc = make_float4(0.f, 0.f, 0.f, 0.f);
            #pragma unroll 4
            for (int j4 = 0; j4 < 64; j4 += 4) {
                const float4 h4 = *(const float4*)&xs[n][j4];
                #pragma unroll
                for (int jj = 0; jj < 4; ++jj) {
                    const float4 wr = *(const float4*)&W2s[j4 + jj][d0];
                    const float hv = (&h4.x)[jj];
                    acc.x = fmaf(hv, wr.x, acc.x);
                    acc.y = fmaf(hv, wr.y, acc.y);
                    acc.z = fmaf(hv, wr.z, acc.z);
                    acc.w = fmaf(hv, wr.w, acc.w);
                }
            }
            float4 res;
            #pragma unroll
            for (int j = 0; j < 4; ++j) {
                const int d = d0 + j;
                const float v = (&acc.x)[j] + b2s[d];
                const uint32_t idx = (uint32_t)(b * 2048 + n * 16 + d);
                const float nz = jax_normal_elem(ky0, ky1, idx);
                const float yhv = v + stdyv[d] * nz;
                yh[n][d] = yhv;
                (&res.x)[j] = yhv;
            }
            *(float4*)&out[(((size_t)t * 64 + b) * 128 + n) * 16 + d0] = res;
        }
        __syncthreads();

        // phase 5: logw (constant shift terms cancel in argmax; omit them)
        if (tid < 128) {
            float s = 0.f;
            for (int d = 0; d < 16; ++d) {
                const float dd = yh[tid][d] - ykv[d];
                s += (dd * dd) / sigyv[d];
            }
            logw[tid] = -0.5f * s;
        }
        __syncthreads();

        // phase 6: categorical via gumbel argmax. gumbel shape (128,64,128),
        // flat idx = p*8192 + b*128 + n, one cipher per element (partitionable).
        {
            const int p = tid >> 2;   // draw row 0..127
            const int sub = tid & 3;  // 4 threads per draw, 32 categories each
            float best = -3.402823466e+38f;
            int bi = 0;
            const uint32_t base_idx = (uint32_t)p * 8192u + (uint32_t)b * 128u;
            for (int m = 0; m < 32; ++m) {
                const int n = (sub << 5) + m;
                const float v = logw[n] + gumbel_from_bits(jax_random_bits(kc0, kc1, base_idx + (uint32_t)n));
                if (v > best) { best = v; bi = n; }
            }
            #pragma unroll
            for (int off = 1; off < 4; off <<= 1) {
                const float ov = __shfl_xor(best, off);
                const int   oi = __shfl_xor(bi, off);
                if (ov > best || (ov == best && oi < bi)) { best = ov; bi = oi; }
            }
            if (sub == 0) anc[p] = bi;
        }
        __syncthreads();

        // phase 7: resample xs[n] = xn[anc[n]]
        for (int it = tid; it < 2048; it += TB) {
            const int n = it >> 4, q = (it & 15) * 4;
            *(float4*)&xs[n][q] = *(const float4*)&xn[anc[n]][q];
        }
        __syncthreads();
    }
}

extern "C" void kernel_launch(void* const* d_in, const int* in_sizes, int n_in,
                              void* d_out, int out_size, void* d_ws, size_t ws_size,
                              hipStream_t stream) {
    const float* u    = (const float*)d_in[0];
    const float* y    = (const float*)d_in[1];
    const float* W_ih = (const float*)d_in[2];
    const float* W_hh = (const float*)d_in[3];
    const float* b_ih = (const float*)d_in[4];
    const float* b_hh = (const float*)d_in[5];
    const float* W1   = (const float*)d_in[6];
    const float* b1   = (const float*)d_in[7];
    const float* W2   = (const float*)d_in[8];
    const float* b2   = (const float*)d_in[9];
    const float* sigx = (const float*)d_in[10];
    const float* sigy = (const float*)d_in[11];
    float* out = (float*)d_out;
    hipLaunchKernelGGL(smc_kernel, dim3(64), dim3(TB), 0, stream,
                       u, y, W_ih, W_hh, b_ih, b_hh, W1, b1, W2, b2, sigx, sigy, out);
}